// Round 2
// baseline (760.808 us; speedup 1.0000x reference)
//
#include <hip/hip_runtime.h>
#include <math.h>

// feat_1: (16,32,256,256) f32; feat_2: (16,32,64,64) f32; xcorr/out: (16,32,319,319) f32
#define BLOCK 256
#define SEG   2          // row segments per channel -> grid = SEG x 512 blocks
#define H1    256
#define W1    256
#define HO    319
#define WO    319
#define BC    512        // B*C

__device__ __forceinline__ float block_reduce_sum(float val, float* scratch, int tid) {
  #pragma unroll
  for (int off = 32; off >= 1; off >>= 1) val += __shfl_xor(val, off, 64);
  if ((tid & 63) == 0) scratch[tid >> 6] = val;
  __syncthreads();
  float r = scratch[0] + scratch[1] + scratch[2] + scratch[3];
  __syncthreads();
  return r;
}

__device__ __forceinline__ float out_val(double ws, double ws2, float xc,
                                         float mean, float ssd) {
  const float FLOOR_ = 1.1920928955078125e-07f;   // float32 eps
  const float CEIL_  = 3.4028234663852886e+38f;   // float32 max
  float wsf  = (float)ws;
  float num  = xc - wsf * mean;
  // winsum2 - winsum^2/4096 in fp64: exact even when true value ~1e-6
  double w2cd = ws2 - ws * ws * (1.0 / 4096.0);
  float w2c  = (float)w2cd;
  float den  = sqrtf(fmaxf(w2c * ssd, 0.0f));
  float numc = fminf(fmaxf(num, FLOOR_), CEIL_);
  return (den > FLOOR_) ? (numc / den) : 0.0f;
}

__global__ __launch_bounds__(BLOCK)
void ncc_norm_kernel(const float* __restrict__ feat1,
                     const float* __restrict__ feat2,
                     const float* __restrict__ xcorr,
                     float* __restrict__ out) {
  __shared__ double psv[W1];      // inclusive prefix of vertical window sums
  __shared__ double psv2[W1];     // inclusive prefix of vertical sums of squares
  __shared__ double waveS[4], waveS2[4];
  __shared__ float scratch[4];

  const int tid  = threadIdx.x;      // == column x of feat_1
  const int lane = tid & 63;
  const int wv   = tid >> 6;
  const int bc   = blockIdx.y;       // channel (b*C+c)
  const int seg  = blockIdx.x;

  const int rows_per = (HO + SEG - 1) / SEG;   // 160
  const int y0 = seg * rows_per;
  const int y1 = min(HO, y0 + rows_per);

  const float* f1 = feat1 + (size_t)bc * (H1 * W1);
  const float* f2 = feat2 + (size_t)bc * 4096;

  // ---- per-channel feat_2 stats: mean and sum((x-mean)^2) ----
  float vals[16];
  float s = 0.0f;
  #pragma unroll
  for (int i = 0; i < 16; ++i) { vals[i] = f2[i * 256 + tid]; s += vals[i]; }
  float tot  = block_reduce_sum(s, scratch, tid);
  float mean = tot * (1.0f / 4096.0f);
  float s2 = 0.0f;
  #pragma unroll
  for (int i = 0; i < 16; ++i) { float d = vals[i] - mean; s2 += d * d; }
  float ssd = block_reduce_sum(s2, scratch, tid);

  // ---- init vertical running window sums (fp64) for output row y0-1 ----
  // V[y][x] = sum_{r in [max(0,y-63), min(255,y)]} f1[r][x]
  double v = 0.0, v2 = 0.0;
  for (int r = max(0, y0 - 64); r <= min(H1 - 1, y0 - 1); ++r) {
    float t = f1[r * W1 + tid];
    double td = (double)t;
    v += td; v2 += td * td;
  }

  for (int y = y0; y < y1; ++y) {
    // slide: add entering row y, subtract leaving row y-64
    if (y < H1) {
      float t = f1[y * W1 + tid];
      double td = (double)t;
      v += td; v2 += td * td;
    }
    int yl = y - 64;
    if (yl >= 0) {
      float t = f1[yl * W1 + tid];
      double td = (double)t;
      v -= td; v2 -= td * td;
    }

    // 256-wide inclusive prefix scan of (v, v2) in fp64
    double pv = v, pv2 = v2;
    #pragma unroll
    for (int off = 1; off < 64; off <<= 1) {
      double a = __shfl_up(pv,  (unsigned)off, 64);
      double b = __shfl_up(pv2, (unsigned)off, 64);
      if (lane >= off) { pv += a; pv2 += b; }
    }
    if (lane == 63) { waveS[wv] = pv; waveS2[wv] = pv2; }
    __syncthreads();
    double base = 0.0, base2 = 0.0;
    for (int i = 0; i < wv; ++i) { base += waveS[i]; base2 += waveS2[i]; }
    psv[tid]  = pv  + base;
    psv2[tid] = pv2 + base2;
    __syncthreads();

    // horizontal window sums + fused epilogue
    const size_t rowbase = ((size_t)bc * HO + y) * WO;
    {
      int xo = tid;                        // 0..255
      double ws = psv[xo], ws2 = psv2[xo];
      if (xo >= 64) { ws -= psv[xo - 64]; ws2 -= psv2[xo - 64]; }
      float xc = xcorr[rowbase + xo];
      out[rowbase + xo] = out_val(ws, ws2, xc, mean, ssd);
    }
    if (tid < WO - BLOCK) {                // xo = 256..318
      int xo = tid + BLOCK;
      double ws  = psv[W1 - 1]  - psv[xo - 64];
      double ws2 = psv2[W1 - 1] - psv2[xo - 64];
      float xc = xcorr[rowbase + xo];
      out[rowbase + xo] = out_val(ws, ws2, xc, mean, ssd);
    }
    // next iteration's LDS writes are fenced by its own __syncthreads()
  }
}

extern "C" void kernel_launch(void* const* d_in, const int* in_sizes, int n_in,
                              void* d_out, int out_size, void* d_ws, size_t ws_size,
                              hipStream_t stream) {
  const float* feat1 = (const float*)d_in[0];
  const float* feat2 = (const float*)d_in[1];
  const float* xcorr = (const float*)d_in[2];
  float* out = (float*)d_out;

  dim3 grid(SEG, BC);
  ncc_norm_kernel<<<grid, BLOCK, 0, stream>>>(feat1, feat2, xcorr, out);
}

// Round 3
// 553.929 us; speedup vs baseline: 1.3735x; 1.3735x over previous
//
#include <hip/hip_runtime.h>
#include <math.h>

// feat_1: (16,32,256,256) f32; feat_2: (16,32,64,64) f32; xcorr/out: (16,32,319,319) f32
#define H1 256
#define W1 256
#define HO 319
#define WO 319
#define SEG 8            // row segments per channel; one WAVE per (channel, segment)
#define ROWS_PER 40      // ceil(319/8)

__device__ __forceinline__ float up0(float x, int d, int lane) {
  float s = __shfl_up(x, (unsigned)d, 64);
  return (lane >= d) ? s : 0.0f;
}
__device__ __forceinline__ float dn0(float x, int d, int lane) {
  float s = __shfl_down(x, (unsigned)d, 64);
  return (lane + d <= 63) ? s : 0.0f;
}

// Given this lane's 4 column values a0..a3 (cols 4*lane .. 4*lane+3, all >= 0),
// produce the 64-wide windowed sums:
//   wi[j]: window ending at xo = 4*lane+j        (interior, clipped at 0)
//   wt[j]: window ending at xo = 256+4*lane+j    (tail, clipped at 255)
// All values are built from ADDITIONS of in-window values only -> no cancellation.
__device__ __forceinline__ void win7(float a0, float a1, float a2, float a3,
                                     int lane, float wi[4], float wt[4]) {
  float L0 = a0, L1 = L0 + a1, L2 = L1 + a2, L3 = L2 + a3;  // in-thread prefixes
  float sf2 = a3, sf1 = sf2 + a2, sf0 = sf1 + a1;           // in-thread suffixes (slots > j)
  // backward windowed sums of thread totals (pow2 doubling)
  float b1 = L3 + up0(L3, 1, lane);   // 2-window incl
  float b2 = b1 + up0(b1, 2, lane);   // 4-window incl
  float b3 = b2 + up0(b2, 4, lane);   // 8-window incl
  // M = sum of totals over lanes [lane-15, lane-1] (clipped at 0): 8+4+2+1 decomposition
  float M = up0(b3, 1, lane) + up0(b2, 9, lane) + up0(b1, 13, lane) + up0(L3, 15, lane);
  // forward 16-window inclusive of totals (for right-clipped tail windows)
  float c1 = L3 + dn0(L3, 1, lane);
  float c2 = c1 + dn0(c1, 2, lane);
  float c3 = c2 + dn0(c2, 4, lane);
  float c4 = c3 + dn0(c3, 8, lane);
  float T49 = dn0(c4, 49, lane);      // sum of totals over lanes [lane+49, 63]
  // partial-thread pieces from lane-16 (interior) and lane+48 (tail)
  float g0 = up0(sf0, 16, lane), g1 = up0(sf1, 16, lane), g2 = up0(sf2, 16, lane);
  float h0 = dn0(sf0, 48, lane), h1 = dn0(sf1, 48, lane), h2 = dn0(sf2, 48, lane);
  wi[0] = g0 + M + L0;  wi[1] = g1 + M + L1;  wi[2] = g2 + M + L2;  wi[3] = M + L3;
  wt[0] = h0 + T49;     wt[1] = h1 + T49;     wt[2] = h2 + T49;     wt[3] = T49;
}

__device__ __forceinline__ float out_val(float ws, float ws2, float xc,
                                         float mean, float ssd) {
  const float FLOOR_  = 1.1920928955078125e-07f;  // float32 eps
  const float FLOOR2_ = FLOOR_ * FLOOR_;
  float num  = xc - ws * mean;
  float w2c  = ws2 - ws * ws * (1.0f / 4096.0f);
  float t    = fmaxf(w2c * ssd, 0.0f);            // denom^2
  float numc = fmaxf(num, FLOOR_);                // (num << FLT_MAX always; skip upper clip)
  return (t > FLOOR2_) ? (numc * __frsqrt_rn(t)) : 0.0f;
}

__global__ __launch_bounds__(256)
void ncc_norm_kernel(const float* __restrict__ feat1,
                     const float* __restrict__ feat2,
                     const float* __restrict__ xcorr,
                     float* __restrict__ out) {
  const int tid  = threadIdx.x;
  const int lane = tid & 63;
  const int wv   = tid >> 6;
  const int bc   = blockIdx.y;                 // channel
  const int seg  = blockIdx.x * 4 + wv;        // 0..7, one wave per segment

  const float* f1 = feat1 + (size_t)bc * (H1 * W1);
  const float* f2 = feat2 + (size_t)bc * 4096;

  // ---- per-wave feat_2 stats (no cross-wave sync needed) ----
  float sum = 0.0f, sumsq = 0.0f;
  #pragma unroll
  for (int r = 0; r < 16; ++r) {
    float4 q = *(const float4*)(f2 + r * 256 + 4 * lane);
    sum   += (q.x + q.y) + (q.z + q.w);
    sumsq += (q.x * q.x + q.y * q.y) + (q.z * q.z + q.w * q.w);
  }
  #pragma unroll
  for (int d = 1; d < 64; d <<= 1) {
    sum   += __shfl_xor(sum,   d, 64);
    sumsq += __shfl_xor(sumsq, d, 64);
  }
  float mean = sum * (1.0f / 4096.0f);
  float ssd  = sumsq - sum * mean;   // sum((x-mean)^2); terms ~4096 vs ~1, no cancellation

  const int y0 = seg * ROWS_PER;
  const int y1 = min(HO, y0 + ROWS_PER);
  const int x4 = 4 * lane;

  // ---- vertical running window sums (fp64 registers; exact to ~1e-12) ----
  double v0 = 0, v1 = 0, v2 = 0, v3 = 0;      // sum of f1 over vertical window, per slot
  double q0 = 0, q1 = 0, q2 = 0, q3 = 0;      // sum of f1^2
  for (int r = max(0, y0 - 64); r < min(y0, H1); ++r) {
    float4 t = *(const float4*)(f1 + r * W1 + x4);
    v0 += t.x; q0 += (double)t.x * t.x;
    v1 += t.y; q1 += (double)t.y * t.y;
    v2 += t.z; q2 += (double)t.z * t.z;
    v3 += t.w; q3 += (double)t.w * t.w;
  }

  for (int y = y0; y < y1; ++y) {
    if (y < H1) {                              // entering row (uniform branch)
      float4 t = *(const float4*)(f1 + y * W1 + x4);
      v0 += t.x; q0 += (double)t.x * t.x;
      v1 += t.y; q1 += (double)t.y * t.y;
      v2 += t.z; q2 += (double)t.z * t.z;
      v3 += t.w; q3 += (double)t.w * t.w;
    }
    int yl = y - 64;
    if (yl >= 0) {                             // leaving row (uniform branch)
      float4 t = *(const float4*)(f1 + yl * W1 + x4);
      v0 -= t.x; q0 -= (double)t.x * t.x;
      v1 -= t.y; q1 -= (double)t.y * t.y;
      v2 -= t.z; q2 -= (double)t.z * t.z;
      v3 -= t.w; q3 -= (double)t.w * t.w;
    }

    // fp32 per-column vertical sums for this output row
    float w0 = (float)v0, w1 = (float)v1, w2 = (float)v2, w3 = (float)v3;
    float u0 = (float)q0, u1 = (float)q1, u2 = (float)q2, u3 = (float)q3;

    float wsI[4], wsT[4], sqI[4], sqT[4];
    win7(w0, w1, w2, w3, lane, wsI, wsT);
    win7(u0, u1, u2, u3, lane, sqI, sqT);

    const int rowbase = (bc * HO + y) * WO;
    const float* xr = xcorr + rowbase;
    float*       orw = out  + rowbase;

    // interior outputs xo = 4*lane + j  (rows are 319 floats -> only 4B aligned: scalar I/O)
    #pragma unroll
    for (int j = 0; j < 4; ++j) {
      float xc = xr[x4 + j];
      orw[x4 + j] = out_val(wsI[j], sqI[j], xc, mean, ssd);
    }
    // tail outputs xo = 256 + 4*lane + j (lanes 0..15 only; 63 elements)
    if (lane < 16) {
      #pragma unroll
      for (int j = 0; j < 4; ++j) {
        int xo = 256 + x4 + j;
        if (xo < WO) {
          float xc = xr[xo];
          orw[xo] = out_val(wsT[j], sqT[j], xc, mean, ssd);
        }
      }
    }
  }
}

extern "C" void kernel_launch(void* const* d_in, const int* in_sizes, int n_in,
                              void* d_out, int out_size, void* d_ws, size_t ws_size,
                              hipStream_t stream) {
  const float* feat1 = (const float*)d_in[0];
  const float* feat2 = (const float*)d_in[1];
  const float* xcorr = (const float*)d_in[2];
  float* out = (float*)d_out;

  dim3 grid(SEG / 4, 512);   // 4 waves/block, one wave per (channel, segment)
  ncc_norm_kernel<<<grid, 256, 0, stream>>>(feat1, feat2, xcorr, out);
}